// Round 11
// baseline (1228.350 us; speedup 1.0000x reference)
//
#include <hip/hip_runtime.h>
#include <stdint.h>
#include <stddef.h>

// Conv_M: fused dynamic-filter conv. B=4, Cin=Cout=64, H=W=128, K=3.
// R16 = R15 best +
// (a) k_gemm1 nb-merge 4->2: each block computes 288 cols (18 B-tiles/step,
//     acc[18]=72 VGPR, LDS exactly 64KB -> 2 blk/CU at (512,4)). Halves the
//     4x featb re-read (604->302 MB HBM). Epilogue = 2 passes over the same
//     144-col w1buf. Drain-barrier staging kept (counted-vmcnt falsified
//     for gemm1 in R13/R14).
// (b) k_gemm2 epilogue reg-cache: yr/mr/sr hoisted out of the 4-plane loop
//     (once per chunk, +48 VGPR -> ~112 <= 128 cap). 4x fewer epilogue
//     global reads.
// gemm2 K-loop at its measured structural optimum (LDS ~110 B/cyc of
// 85-128 capability; bigger wave tiles spill (R11), 1 blk/CU slower (R7)).

using short8   = __attribute__((ext_vector_type(8))) short;
using float4v  = __attribute__((ext_vector_type(4))) float;
using ushort4v = __attribute__((ext_vector_type(4))) unsigned short;

#define DI __device__ __forceinline__

DI unsigned short f2bf(float f) {
  union { float f; unsigned int u; } a; a.f = f;
  unsigned int r = a.u + 0x7fffu + ((a.u >> 16) & 1u);
  return (unsigned short)(r >> 16);
}
DI float bf2f(unsigned short u) {
  union { unsigned int u; float f; } a; a.u = ((unsigned int)u) << 16;
  return a.f;
}
DI void gll16(const void* g, void* l) {
  __builtin_amdgcn_global_load_lds(
      (const __attribute__((address_space(1))) unsigned int*)g,
      (__attribute__((address_space(3))) unsigned int*)l, 16, 0, 0);
}

// ---------------------------------------------------------------------------
// feat layout: idx = ((kk*512 + pblk)*4 + q)*1024 + plocal*8 + j8
//   kk = k/32 (36 blocks), pblk = pixel/128 (512), q = (k>>3)&3, j8 = k&7.
// feat col = c*9 + (kh*3+kw) for x (cols 0..575), same +576 for m.
// One thread -> 8 consecutive elems (j8=0..7); store = one short8 (16B);
// lanes = consecutive pl so each of the 8 gathers is wave-coalesced.
// ---------------------------------------------------------------------------
__global__ void k_feat(const float* __restrict__ x, const float* __restrict__ m,
                       unsigned short* __restrict__ featb) {
  unsigned int v = blockIdx.x * 256u + threadIdx.x;   // < 9,437,184
  unsigned int f = v * 8u;                            // flat elem index
  int pl   = (f >> 3) & 127;
  int q    = (f >> 10) & 3;
  int pblk = (f >> 12) & 511;
  int kk   = (int)(f >> 21);
  int base = kk * 32 + q * 8;
  const float* src = x;
  int jb = base;
  if (base >= 576) { src = m; jb = base - 576; }
  int p  = pblk * 128 + pl;
  int b  = p >> 14, h = (p >> 7) & 127;               // w == pl
  short8 o;
#pragma unroll
  for (int j = 0; j < 8; ++j) {
    int jx = jb + j;
    int c  = jx / 9;
    int t  = jx - c * 9;
    int t3 = t / 3;
    int dh = t3 - 1;
    int dw = (t - t3 * 3) - 1;
    int hh = min(max(h + dh, 0), 127);                // replicate pad
    int ww = min(max(pl + dw, 0), 127);
    o[j] = (short)f2bf(src[(((b << 6) | c) << 14) + (hh << 7) + ww]);
  }
  *(short8*)&featb[(size_t)v * 8] = o;
}

// ---------------------------------------------------------------------------
// Weight swizzle (8-wide): src row-major [k][n] fp32 -> bf16 B-frag tiles at
// idx = ((k>>5)*ntiles + (np>>4))*512 + ((k>>3)&3)*128 + (np&15)*8 + (k&7);
// perm=1 (W2): np = (n&63)<<6 | (n>>6). One thread = 8 consecutive k x one n
// -> one short8 store; reads lane-coalesced in n.
// ---------------------------------------------------------------------------
__global__ void k_sw(const float* __restrict__ Wsrc, unsigned short* __restrict__ Wdst,
                     int ncols, int ntiles, int total, int perm) {
  int tid = blockIdx.x * 256 + threadIdx.x;
  if (tid >= total) return;
  int k8 = tid / ncols;            // 0..143: group of 8 k rows
  int n  = tid - k8 * ncols;
  int np = perm ? (((n & 63) << 6) | (n >> 6)) : n;
  int k0 = k8 * 8;
  int obase = ((k0 >> 5) * ntiles + (np >> 4)) * 512 + (k8 & 3) * 128 +
              (np & 15) * 8;       // + j for j=0..7
  short8 o;
#pragma unroll
  for (int j = 0; j < 8; ++j)
    o[j] = (short)f2bf(Wsrc[(size_t)(k0 + j) * ncols + n]);
  *(short8*)&Wdst[obase] = o;
}

// ---------------------------------------------------------------------------
// GEMM1 (R16): w1 = feat@W1 + b1, then yr/mr/sr via 3x3 taps.
// nb-merged 4->2: block = 128 rows x 288 cols (18 tiles), grid (512, 2).
// Per kk: drain-barrier stage A 8KB + B 18.4KB (2 full gll16 + tid<128
// tail), 18 MFMA. acc[18] = 72 VGPR. LDS = 8192 + 18432 + 38912 = 64KB
// exactly -> 2 blocks/CU at (512,4). Halves featb HBM re-read vs nb=4.
// Epilogue: 2 half-passes (144 cols each) over the same w1buf.
// ---------------------------------------------------------------------------
__launch_bounds__(512, 4)
__global__ void k_gemm1(const unsigned short* __restrict__ featb,
                        const unsigned short* __restrict__ W1s,
                        const float* __restrict__ b1,
                        const float* __restrict__ x, const float* __restrict__ m,
                        const float* __restrict__ s,
                        float* __restrict__ yr, float* __restrict__ mr,
                        float* __restrict__ sr) {
  __shared__ __align__(16) unsigned short Alds[4096];       // 8KB  [q][p128][j8]
  __shared__ __align__(16) unsigned short Blds[9216];       // 18432B: 18 tiles
  __shared__ __align__(16) unsigned short w1buf[128 * 152]; // 38912B
  const int tid = threadIdx.x;
  const int wv  = tid >> 6;
  const int l15 = tid & 15;
  const int q   = (tid >> 4) & 3;
  const int bm  = blockIdx.x, nb2 = blockIdx.y;  // nb2 in 0..1

  float4v acc[18];
#pragma unroll
  for (int t = 0; t < 18; ++t) acc[t] = (float4v){0.f, 0.f, 0.f, 0.f};

  const unsigned short* Ab = featb + (size_t)bm * 4096;
  const unsigned short* Bb = W1s + (size_t)nb2 * 9216;  // tiles 18*nb2..

  for (int kk = 0; kk < 36; ++kk) {
    __syncthreads();
    gll16(Ab + (size_t)kk * 2097152 + tid * 8, (char*)Alds + wv * 1024);
    gll16(Bb + (size_t)kk * 18432 + tid * 8, (char*)Blds + wv * 1024);
    gll16(Bb + (size_t)kk * 18432 + 4096 + tid * 8, (char*)Blds + 8192 + wv * 1024);
    if (tid < 128)
      gll16(Bb + (size_t)kk * 18432 + 8192 + tid * 8,
            (char*)Blds + 16384 + (tid >> 6) * 1024);
    __syncthreads();
    short8 af = *(const short8*)&Alds[q * 1024 + (16 * wv + l15) * 8];
#pragma unroll
    for (int t = 0; t < 18; ++t) {
      short8 bfr = *(const short8*)&Blds[t * 512 + q * 128 + l15 * 8];
      acc[t] = __builtin_amdgcn_mfma_f32_16x16x32_bf16(af, bfr, acc[t], 0, 0, 0);
    }
  }

  const int b = bm >> 7, h = bm & 127;  // m-block = one (b,h) image row
  for (int half = 0; half < 2; ++half) {
    __syncthreads();  // prior w1buf reads (or K-loop LDS use) complete
    // w1 (+bias) -> LDS as bf16. C/D layout: col=lane&15, row=quad*4+i.
#pragma unroll
    for (int t = 0; t < 9; ++t) {
      int col = 16 * t + l15;
      float bb = b1[nb2 * 288 + half * 144 + col];
#pragma unroll
      for (int i = 0; i < 4; ++i) {
        int plr = 16 * wv + 4 * q + i;
        w1buf[plr * 152 + col] = f2bf(acc[9 * half + t][i] + bb);
      }
    }
    __syncthreads();
#pragma unroll
    for (int ii = 0; ii < 4; ++ii) {
      int task = ii * 512 + tid;   // 2048 tasks: (p 0..127) x (cl 0..15)
      int p  = task >> 4;
      int cl = task & 15;
      int c  = nb2 * 32 + half * 16 + cl;
      float w1v[9];
#pragma unroll
      for (int k = 0; k < 9; ++k) w1v[k] = bf2f(w1buf[p * 152 + cl * 9 + k]);
      size_t base = (size_t)(((b << 6) | c) << 14);
      float vy = 0.f, vm = 0.f, vs = 0.f;
#pragma unroll
      for (int dh = -1; dh <= 1; ++dh) {
        int hh = min(max(h + dh, 0), 127);
#pragma unroll
        for (int dw = -1; dw <= 1; ++dw) {
          int ww = min(max(p + dw, 0), 127);
          size_t idx = base + (hh << 7) + ww;
          int k = (dh + 1) * 3 + (dw + 1);
          float wv1 = w1v[k], aw = fabsf(wv1);
          vy += x[idx] * wv1;
          vm += m[idx] * aw;
          vs += s[idx] * aw;
        }
      }
      size_t P = (size_t)bm * 128 + p;
      yr[P * 64 + c] = vy;
      mr[P * 64 + c] = vm;
      sr[P * 64 + c] = vs;
    }
  }
}

// ---------------------------------------------------------------------------
// GEMM2 (R10 K-loop + R16 epilogue reg-cache): block = 128 rows x 256
// cols/chunk, 16 chunks, 512 blocks, 2 blocks/CU (72KB LDS: 3x24KB units,
// w2buf aliased into U[2]). Per kk: vmcnt(3) -> barrier -> stage kk+2
// (3 gll16) -> 8 ds_read -> 16 MFMA in setprio(1). DRAIN at ch==15, kk>=34.
// Epilogue: yr/mr/sr loaded ONCE per chunk into regs (48 VGPR), then the
// 4 o-planes reuse them (was 4x redundant global reads).
// ---------------------------------------------------------------------------
__launch_bounds__(512, 4)
__global__ void k_gemm2(const unsigned short* __restrict__ featb,
                        const unsigned short* __restrict__ W2s,
                        const float* __restrict__ b2,
                        const float* __restrict__ yr, const float* __restrict__ mr,
                        const float* __restrict__ sr,
                        float* __restrict__ out) {
  __shared__ __align__(16) unsigned short U[3][12288];  // 3 x 24KB: [A 4096 | B 8192] shorts
  unsigned short* w2buf = &U[2][0];                     // aliased: 128*68 = 8704 shorts
  const int tid  = threadIdx.x;
  const int wv   = tid >> 6;     // 0..7
  const int lane = tid & 63;
  const int wm   = wv >> 2;      // 0..1: 64-row half
  const int wn   = wv & 3;       // 0..3: o = 4ch+wn
  const int l15  = tid & 15;
  const int q    = (tid >> 4) & 3;
  const int part = lane >> 4;    // 0..3: 16-c quarter (epilogue)
  const int bm   = blockIdx.x;   // 0..511: rows 128bm..128bm+127 (pblk = bm)

  const unsigned short* Ab = featb + (size_t)bm * 4096;

  float4v acc[4][4];
#pragma unroll
  for (int r = 0; r < 4; ++r)
#pragma unroll
    for (int t = 0; t < 4; ++t) acc[r][t] = (float4v){0.f, 0.f, 0.f, 0.f};

  // epilogue row/pointers (fixed per thread)
  const int erow = 16 * wv + l15;
  const size_t eP = (size_t)bm * 128 + erow;
  const float4v* ey4 = (const float4v*)(yr + eP * 64 + 16 * part);
  const float4v* em4 = (const float4v*)(mr + eP * 64 + 16 * part);
  const float4v* es4 = (const float4v*)(sr + eP * 64 + 16 * part);

  // prologue: stage kk=0 -> U[0], kk=1 -> U[1]
  gll16(Ab + tid * 8,                  (char*)&U[0][0]    + wv * 1024);
  gll16(W2s + tid * 8,                 (char*)&U[0][4096] + wv * 1024);
  gll16(W2s + 4096 + tid * 8,          (char*)&U[0][8192] + wv * 1024);
  gll16(Ab + 2097152 + tid * 8,        (char*)&U[1][0]    + wv * 1024);
  gll16(W2s + 131072 + tid * 8,        (char*)&U[1][4096] + wv * 1024);
  gll16(W2s + 131072 + 4096 + tid * 8, (char*)&U[1][8192] + wv * 1024);

#define G2_KK(KK, BR, BS, DRAIN)                                               \
  do {                                                                         \
    int kks = (KK) + 2, chs = ch;                                              \
    if (kks >= 36) { kks -= 36; chs += 1; }                                    \
    if (DRAIN) { asm volatile("s_waitcnt vmcnt(0)" ::: "memory"); }            \
    else       { asm volatile("s_waitcnt vmcnt(3)" ::: "memory"); }            \
    __builtin_amdgcn_s_barrier();                                              \
    asm volatile("" ::: "memory");                                             \
    if (chs < 16) {                                                            \
      const unsigned short* Ag = Ab + (size_t)kks * 2097152;                   \
      const unsigned short* Bg = W2s + (size_t)kks * 131072 + (size_t)chs * 8192; \
      gll16(Ag + tid * 8,        (char*)&U[BS][0]    + wv * 1024);             \
      gll16(Bg + tid * 8,        (char*)&U[BS][4096] + wv * 1024);             \
      gll16(Bg + 4096 + tid * 8, (char*)&U[BS][8192] + wv * 1024);             \
    }                                                                          \
    {                                                                          \
      const unsigned short* Al = &U[BR][0];                                    \
      const unsigned short* Bl = &U[BR][4096];                                 \
      short8 a_[4];                                                            \
      _Pragma("unroll") for (int r = 0; r < 4; ++r)                            \
        a_[r] = *(const short8*)&Al[q * 1024 + (64 * wm + 16 * r + l15) * 8];  \
      __builtin_amdgcn_s_setprio(1);                                           \
      _Pragma("unroll") for (int t = 0; t < 4; ++t) {                          \
        short8 bfr = *(const short8*)&Bl[(4 * wn + t) * 512 + q * 128 + l15 * 8]; \
        _Pragma("unroll") for (int r = 0; r < 4; ++r)                          \
          acc[r][t] = __builtin_amdgcn_mfma_f32_16x16x32_bf16(a_[r], bfr,      \
                                                              acc[r][t], 0, 0, 0); \
      }                                                                        \
      __builtin_amdgcn_s_setprio(0);                                           \
    }                                                                          \
  } while (0)

  for (int ch = 0; ch < 16; ++ch) {
    const bool lc = (ch == 15);
    for (int k3 = 0; k3 < 12; ++k3) {
      const int kk = k3 * 3;   // 36 % 3 == 0 -> every chunk starts at buf 0
      G2_KK(kk + 0, 0, 2, false);
      G2_KK(kk + 1, 1, 0, (lc && k3 == 11));
      G2_KK(kk + 2, 2, 1, (lc && k3 == 11));
    }

    // ---- epilogue: load yr/mr/sr ONCE per chunk, then 4 o-planes.
    float4v yv4[4], mv4[4], sv4[4];
#pragma unroll
    for (int j4 = 0; j4 < 4; ++j4) {
      yv4[j4] = ey4[j4];
      mv4[j4] = em4[j4];
      sv4[j4] = es4[j4];
    }
    float b2v[4];
#pragma unroll
    for (int t = 0; t < 4; ++t) b2v[t] = b2[(16 * t + l15) * 64 + 4 * ch + wn];

    for (int p = 0; p < 4; ++p) {
      __syncthreads();           // w2buf free (K-loop reads / prior plane done)
      if (wn == p) {
#pragma unroll
        for (int r = 0; r < 4; ++r)
#pragma unroll
          for (int t = 0; t < 4; ++t)
#pragma unroll
            for (int i = 0; i < 4; ++i)
              w2buf[(64 * wm + 16 * r + 4 * q + i) * 68 + 16 * t + l15] =
                  f2bf(acc[r][t][i] + b2v[t]);
      }
      __syncthreads();
      const ushort4v* w4 = (const ushort4v*)&w2buf[erow * 68 + 16 * part];
      float ys = 0.f, ms = 0.f, ss = 0.f;
#pragma unroll
      for (int j4 = 0; j4 < 4; ++j4) {
        ushort4v wq = w4[j4];
#pragma unroll
        for (int j = 0; j < 4; ++j) {
          float w2f = bf2f(wq[j]);
          float aw  = fabsf(w2f);
          ys += yv4[j4][j] * w2f;
          ms += mv4[j4][j] * aw;
          ss += sv4[j4][j] * aw;
        }
      }
      ys += __shfl_xor(ys, 16); ys += __shfl_xor(ys, 32);
      ms += __shfl_xor(ms, 16); ms += __shfl_xor(ms, 32);
      ss += __shfl_xor(ss, 16); ss += __shfl_xor(ss, 32);
      if (part == 0) {
        const int o = 4 * ch + p;
        const int b = (int)(eP >> 14), h = (int)((eP >> 7) & 127), w = (int)(eP & 127);
        size_t idx = ((size_t)((b << 6) | o) << 14) + (h << 7) + w;
        out[idx]           = ys;
        out[4194304 + idx] = ms / ss;
        out[8388608 + idx] = 1.0f;
      }
    }
    // reset accumulators for next chunk
#pragma unroll
    for (int r = 0; r < 4; ++r)
#pragma unroll
      for (int t = 0; t < 4; ++t) acc[r][t] = (float4v){0.f, 0.f, 0.f, 0.f};
  }
#undef G2_KK
}

// ---------------------------------------------------------------------------
extern "C" void kernel_launch(void* const* d_in, const int* in_sizes, int n_in,
                              void* d_out, int out_size, void* d_ws, size_t ws_size,
                              hipStream_t stream) {
  const float* x  = (const float*)d_in[0];
  const float* m  = (const float*)d_in[1];
  const float* s  = (const float*)d_in[2];
  const float* W1 = (const float*)d_in[3];
  const float* b1 = (const float*)d_in[4];
  const float* W2 = (const float*)d_in[5];
  const float* b2 = (const float*)d_in[6];
  float* out = (float*)d_out;

  // ws layout (bytes):
  //   feat  bf16 : [0, 150994944)               36*65536*32 elems
  //   W1s   bf16 : [150994944, 152322048)       1152*576
  //   W2s   bf16 : [152322048, 161759232)       1152*4096 (o-major permuted)
  //   yr/mr/sr f32: 3 x 16777216 from 161759232 ; end = 212090880
  if (ws_size < 212090880ull) return;
  char* ws = (char*)d_ws;
  unsigned short* featb = (unsigned short*)ws;
  unsigned short* W1s   = (unsigned short*)(ws + 150994944);
  unsigned short* W2s   = (unsigned short*)(ws + 152322048);
  float* yr = (float*)(ws + 161759232);
  float* mr = (float*)(ws + 178536448);
  float* sr = (float*)(ws + 195313664);

  k_feat<<<36864, 256, 0, stream>>>(x, m, featb);
  k_sw<<<324, 256, 0, stream>>>(W1, W1s, 576, 36, 82944, 0);
  k_sw<<<2304, 256, 0, stream>>>(W2, W2s, 4096, 256, 589824, 1);
  dim3 g1(512, 2);
  k_gemm1<<<g1, 512, 0, stream>>>(featb, W1s, b1, x, m, s, yr, mr, sr);
  k_gemm2<<<512, 512, 0, stream>>>(featb, W2s, b2, yr, mr, sr, out);
}

// Round 12
// 1097.282 us; speedup vs baseline: 1.1194x; 1.1194x over previous
//
#include <hip/hip_runtime.h>
#include <stdint.h>
#include <stddef.h>

// Conv_M: fused dynamic-filter conv. B=4, Cin=Cout=64, H=W=128, K=3.
// R17 = exact revert to R15 (verified best, 1108.5 µs).
// R16 post-mortem: (a) gemm2 epilogue reg-cache spilled (WRITE_SIZE 166->377
// MB; 64 acc + 48 cache + 16 a_ + misc > 128-reg cap at 2 blk/CU) — second
// spill incident; rule: no reg-residency increase in gemm2's K-loop-live
// region. (b) gemm1 nb-merge neutral (featb re-read not the binder).
// Session ladder: 1430 (R0 baseline) -> 1242 (R10 gemm2 counted-vmcnt 3-buf
// + w2buf alias, 2 blk/CU) -> 1118.9 (R12 k_feat 8-wide) -> 1108.5 (R15
// k_sw 8-wide). gemm2 at structural plateau: MFMA 36%, LDS ~110 B/cyc
// (near b128 ceiling), HBM 33%, conflicts 0 — all single-resource fixes
// tried and measured worse (R9 phases, R11/R16 regs, R12 rotation).

using short8   = __attribute__((ext_vector_type(8))) short;
using float4v  = __attribute__((ext_vector_type(4))) float;
using ushort4v = __attribute__((ext_vector_type(4))) unsigned short;

#define DI __device__ __forceinline__

DI unsigned short f2bf(float f) {
  union { float f; unsigned int u; } a; a.f = f;
  unsigned int r = a.u + 0x7fffu + ((a.u >> 16) & 1u);
  return (unsigned short)(r >> 16);
}
DI float bf2f(unsigned short u) {
  union { unsigned int u; float f; } a; a.u = ((unsigned int)u) << 16;
  return a.f;
}
DI void gll16(const void* g, void* l) {
  __builtin_amdgcn_global_load_lds(
      (const __attribute__((address_space(1))) unsigned int*)g,
      (__attribute__((address_space(3))) unsigned int*)l, 16, 0, 0);
}

// ---------------------------------------------------------------------------
// feat layout: idx = ((kk*512 + pblk)*4 + q)*1024 + plocal*8 + j8
//   kk = k/32 (36 blocks), pblk = pixel/128 (512), q = (k>>3)&3, j8 = k&7.
// feat col = c*9 + (kh*3+kw) for x (cols 0..575), same +576 for m.
// One thread -> 8 consecutive elems (j8=0..7); store = one short8 (16B);
// lanes = consecutive pl so each of the 8 gathers is wave-coalesced.
// ---------------------------------------------------------------------------
__global__ void k_feat(const float* __restrict__ x, const float* __restrict__ m,
                       unsigned short* __restrict__ featb) {
  unsigned int v = blockIdx.x * 256u + threadIdx.x;   // < 9,437,184
  unsigned int f = v * 8u;                            // flat elem index
  int pl   = (f >> 3) & 127;
  int q    = (f >> 10) & 3;
  int pblk = (f >> 12) & 511;
  int kk   = (int)(f >> 21);
  int base = kk * 32 + q * 8;
  const float* src = x;
  int jb = base;
  if (base >= 576) { src = m; jb = base - 576; }
  int p  = pblk * 128 + pl;
  int b  = p >> 14, h = (p >> 7) & 127;               // w == pl
  short8 o;
#pragma unroll
  for (int j = 0; j < 8; ++j) {
    int jx = jb + j;
    int c  = jx / 9;
    int t  = jx - c * 9;
    int t3 = t / 3;
    int dh = t3 - 1;
    int dw = (t - t3 * 3) - 1;
    int hh = min(max(h + dh, 0), 127);                // replicate pad
    int ww = min(max(pl + dw, 0), 127);
    o[j] = (short)f2bf(src[(((b << 6) | c) << 14) + (hh << 7) + ww]);
  }
  *(short8*)&featb[(size_t)v * 8] = o;
}

// ---------------------------------------------------------------------------
// Weight swizzle (8-wide): src row-major [k][n] fp32 -> bf16 B-frag tiles at
// idx = ((k>>5)*ntiles + (np>>4))*512 + ((k>>3)&3)*128 + (np&15)*8 + (k&7);
// perm=1 (W2): np = (n&63)<<6 | (n>>6). One thread = 8 consecutive k x one n
// -> one short8 store; reads lane-coalesced in n.
// ---------------------------------------------------------------------------
__global__ void k_sw(const float* __restrict__ Wsrc, unsigned short* __restrict__ Wdst,
                     int ncols, int ntiles, int total, int perm) {
  int tid = blockIdx.x * 256 + threadIdx.x;
  if (tid >= total) return;
  int k8 = tid / ncols;            // 0..143: group of 8 k rows
  int n  = tid - k8 * ncols;
  int np = perm ? (((n & 63) << 6) | (n >> 6)) : n;
  int k0 = k8 * 8;
  int obase = ((k0 >> 5) * ntiles + (np >> 4)) * 512 + (k8 & 3) * 128 +
              (np & 15) * 8;       // + j for j=0..7
  short8 o;
#pragma unroll
  for (int j = 0; j < 8; ++j)
    o[j] = (short)f2bf(Wsrc[(size_t)(k0 + j) * ncols + n]);
  *(short8*)&Wdst[obase] = o;
}

// ---------------------------------------------------------------------------
// GEMM1 (R12-verified): w1 = feat@W1 + b1, then yr/mr/sr via 3x3 taps.
// Drain-barrier dbuf staging (counted-vmcnt falsified R13/R14; nb-merge
// neutral R16).
// ---------------------------------------------------------------------------
__launch_bounds__(512, 2)
__global__ void k_gemm1(const unsigned short* __restrict__ featb,
                        const unsigned short* __restrict__ W1s,
                        const float* __restrict__ b1,
                        const float* __restrict__ x, const float* __restrict__ m,
                        const float* __restrict__ s,
                        float* __restrict__ yr, float* __restrict__ mr,
                        float* __restrict__ sr) {
  __shared__ __align__(16) unsigned short Alds[4096];       // 8KB  [q][p128][j8]
  __shared__ __align__(16) unsigned short Blds[4608];       // 9216B: 9 tiles
  __shared__ __align__(16) unsigned short w1buf[128 * 152]; // 38912B
  const int tid = threadIdx.x;
  const int wv  = tid >> 6;
  const int l15 = tid & 15;
  const int q   = (tid >> 4) & 3;
  const int bm  = blockIdx.x, nb = blockIdx.y;

  float4v acc[9];
#pragma unroll
  for (int t = 0; t < 9; ++t) acc[t] = (float4v){0.f, 0.f, 0.f, 0.f};

  const unsigned short* Ab = featb + (size_t)bm * 4096;
  const unsigned short* Bb = W1s + (size_t)nb * 9 * 512;

  for (int kk = 0; kk < 36; ++kk) {
    __syncthreads();
    gll16(Ab + (size_t)kk * 2097152 + tid * 8, (char*)Alds + wv * 1024);
    gll16(Bb + (size_t)kk * 18432 + tid * 8, (char*)Blds + wv * 1024);
    if (tid < 64) gll16(Bb + (size_t)kk * 18432 + 4096 + tid * 8, (char*)Blds + 8192);
    __syncthreads();
    short8 af = *(const short8*)&Alds[q * 1024 + (16 * wv + l15) * 8];
#pragma unroll
    for (int t = 0; t < 9; ++t) {
      short8 bfr = *(const short8*)&Blds[t * 512 + q * 128 + l15 * 8];
      acc[t] = __builtin_amdgcn_mfma_f32_16x16x32_bf16(af, bfr, acc[t], 0, 0, 0);
    }
  }

  // w1 (+bias) -> LDS as bf16. C/D layout: col=lane&15, row=quad*4+i.
#pragma unroll
  for (int t = 0; t < 9; ++t) {
    int col = 16 * t + l15;
    float bb = b1[nb * 144 + col];
#pragma unroll
    for (int i = 0; i < 4; ++i) {
      int plr = 16 * wv + 4 * q + i;
      w1buf[plr * 152 + col] = f2bf(acc[t][i] + bb);
    }
  }
  __syncthreads();

  const int b = bm >> 7, h = bm & 127;  // m-block = one (b,h) image row
#pragma unroll
  for (int ii = 0; ii < 4; ++ii) {
    int task = ii * 512 + tid;     // 2048 tasks: (p 0..127) x (cl 0..15)
    int p  = task >> 4;
    int cl = task & 15;
    int c  = nb * 16 + cl;
    float w1v[9];
#pragma unroll
    for (int k = 0; k < 9; ++k) w1v[k] = bf2f(w1buf[p * 152 + cl * 9 + k]);
    size_t base = (size_t)(((b << 6) | c) << 14);
    float vy = 0.f, vm = 0.f, vs = 0.f;
#pragma unroll
    for (int dh = -1; dh <= 1; ++dh) {
      int hh = min(max(h + dh, 0), 127);
#pragma unroll
      for (int dw = -1; dw <= 1; ++dw) {
        int ww = min(max(p + dw, 0), 127);
        size_t idx = base + (hh << 7) + ww;
        int k = (dh + 1) * 3 + (dw + 1);
        float wv1 = w1v[k], aw = fabsf(wv1);
        vy += x[idx] * wv1;
        vm += m[idx] * aw;
        vs += s[idx] * aw;
      }
    }
    size_t P = (size_t)bm * 128 + p;
    yr[P * 64 + c] = vy;
    mr[P * 64 + c] = vm;
    sr[P * 64 + c] = vs;
  }
}

// ---------------------------------------------------------------------------
// GEMM2 (R10 verified): block = 128 rows x 256 cols/chunk, 16 chunks,
// 512 blocks, 2 blocks/CU (72KB LDS: 3x24KB units, w2buf aliased into U[2]).
// Per kk: vmcnt(3) -> barrier -> stage kk+2 (3 gll16) -> 8 ds_read ->
// 16 MFMA in setprio(1). DRAIN vmcnt(0) at ch==15, kk>=34.
// ---------------------------------------------------------------------------
__launch_bounds__(512, 4)
__global__ void k_gemm2(const unsigned short* __restrict__ featb,
                        const unsigned short* __restrict__ W2s,
                        const float* __restrict__ b2,
                        const float* __restrict__ yr, const float* __restrict__ mr,
                        const float* __restrict__ sr,
                        float* __restrict__ out) {
  __shared__ __align__(16) unsigned short U[3][12288];  // 3 x 24KB: [A 4096 | B 8192] shorts
  unsigned short* w2buf = &U[2][0];                     // aliased: 128*68 = 8704 shorts
  const int tid  = threadIdx.x;
  const int wv   = tid >> 6;     // 0..7
  const int lane = tid & 63;
  const int wm   = wv >> 2;      // 0..1: 64-row half
  const int wn   = wv & 3;       // 0..3: o = 4ch+wn
  const int l15  = tid & 15;
  const int q    = (tid >> 4) & 3;
  const int part = lane >> 4;    // 0..3: 16-c quarter (epilogue)
  const int bm   = blockIdx.x;   // 0..511: rows 128bm..128bm+127 (pblk = bm)

  const unsigned short* Ab = featb + (size_t)bm * 4096;

  float4v acc[4][4];
#pragma unroll
  for (int r = 0; r < 4; ++r)
#pragma unroll
    for (int t = 0; t < 4; ++t) acc[r][t] = (float4v){0.f, 0.f, 0.f, 0.f};

  // prologue: stage kk=0 -> U[0], kk=1 -> U[1]
  gll16(Ab + tid * 8,                  (char*)&U[0][0]    + wv * 1024);
  gll16(W2s + tid * 8,                 (char*)&U[0][4096] + wv * 1024);
  gll16(W2s + 4096 + tid * 8,          (char*)&U[0][8192] + wv * 1024);
  gll16(Ab + 2097152 + tid * 8,        (char*)&U[1][0]    + wv * 1024);
  gll16(W2s + 131072 + tid * 8,        (char*)&U[1][4096] + wv * 1024);
  gll16(W2s + 131072 + 4096 + tid * 8, (char*)&U[1][8192] + wv * 1024);

#define G2_KK(KK, BR, BS, DRAIN)                                               \
  do {                                                                         \
    int kks = (KK) + 2, chs = ch;                                              \
    if (kks >= 36) { kks -= 36; chs += 1; }                                    \
    if (DRAIN) { asm volatile("s_waitcnt vmcnt(0)" ::: "memory"); }            \
    else       { asm volatile("s_waitcnt vmcnt(3)" ::: "memory"); }            \
    __builtin_amdgcn_s_barrier();                                              \
    asm volatile("" ::: "memory");                                             \
    if (chs < 16) {                                                            \
      const unsigned short* Ag = Ab + (size_t)kks * 2097152;                   \
      const unsigned short* Bg = W2s + (size_t)kks * 131072 + (size_t)chs * 8192; \
      gll16(Ag + tid * 8,        (char*)&U[BS][0]    + wv * 1024);             \
      gll16(Bg + tid * 8,        (char*)&U[BS][4096] + wv * 1024);             \
      gll16(Bg + 4096 + tid * 8, (char*)&U[BS][8192] + wv * 1024);             \
    }                                                                          \
    {                                                                          \
      const unsigned short* Al = &U[BR][0];                                    \
      const unsigned short* Bl = &U[BR][4096];                                 \
      short8 a_[4];                                                            \
      _Pragma("unroll") for (int r = 0; r < 4; ++r)                            \
        a_[r] = *(const short8*)&Al[q * 1024 + (64 * wm + 16 * r + l15) * 8];  \
      __builtin_amdgcn_s_setprio(1);                                           \
      _Pragma("unroll") for (int t = 0; t < 4; ++t) {                          \
        short8 bfr = *(const short8*)&Bl[(4 * wn + t) * 512 + q * 128 + l15 * 8]; \
        _Pragma("unroll") for (int r = 0; r < 4; ++r)                          \
          acc[r][t] = __builtin_amdgcn_mfma_f32_16x16x32_bf16(a_[r], bfr,      \
                                                              acc[r][t], 0, 0, 0); \
      }                                                                        \
      __builtin_amdgcn_s_setprio(0);                                           \
    }                                                                          \
  } while (0)

  for (int ch = 0; ch < 16; ++ch) {
    const bool lc = (ch == 15);
    for (int k3 = 0; k3 < 12; ++k3) {
      const int kk = k3 * 3;   // 36 % 3 == 0 -> every chunk starts at buf 0
      G2_KK(kk + 0, 0, 2, false);
      G2_KK(kk + 1, 1, 0, (lc && k3 == 11));
      G2_KK(kk + 2, 2, 1, (lc && k3 == 11));
    }

    // ---- epilogue: 4 o-planes via w2buf (= U[2], dead until next chunk's
    // first stage-issue, which is behind that step's head barrier).
    float b2v[4];
#pragma unroll
    for (int t = 0; t < 4; ++t) b2v[t] = b2[(16 * t + l15) * 64 + 4 * ch + wn];

    for (int p = 0; p < 4; ++p) {
      __syncthreads();           // w2buf free (K-loop reads / prior plane done)
      if (wn == p) {
#pragma unroll
        for (int r = 0; r < 4; ++r)
#pragma unroll
          for (int t = 0; t < 4; ++t)
#pragma unroll
            for (int i = 0; i < 4; ++i)
              w2buf[(64 * wm + 16 * r + 4 * q + i) * 68 + 16 * t + l15] =
                  f2bf(acc[r][t][i] + b2v[t]);
      }
      __syncthreads();
      const int row = 16 * wv + l15;
      const size_t P = (size_t)bm * 128 + row;
      const float4v* y4 = (const float4v*)(yr + P * 64 + 16 * part);
      const float4v* m4 = (const float4v*)(mr + P * 64 + 16 * part);
      const float4v* s4 = (const float4v*)(sr + P * 64 + 16 * part);
      const ushort4v* w4 = (const ushort4v*)&w2buf[row * 68 + 16 * part];
      float ys = 0.f, ms = 0.f, ss = 0.f;
#pragma unroll
      for (int j4 = 0; j4 < 4; ++j4) {
        float4v yv = y4[j4], mv = m4[j4], sv = s4[j4];
        ushort4v wq = w4[j4];
#pragma unroll
        for (int j = 0; j < 4; ++j) {
          float w2f = bf2f(wq[j]);
          float aw  = fabsf(w2f);
          ys += yv[j] * w2f;
          ms += mv[j] * aw;
          ss += sv[j] * aw;
        }
      }
      ys += __shfl_xor(ys, 16); ys += __shfl_xor(ys, 32);
      ms += __shfl_xor(ms, 16); ms += __shfl_xor(ms, 32);
      ss += __shfl_xor(ss, 16); ss += __shfl_xor(ss, 32);
      if (part == 0) {
        const int o = 4 * ch + p;
        const int b = (int)(P >> 14), h = (int)((P >> 7) & 127), w = (int)(P & 127);
        size_t idx = ((size_t)((b << 6) | o) << 14) + (h << 7) + w;
        out[idx]           = ys;
        out[4194304 + idx] = ms / ss;
        out[8388608 + idx] = 1.0f;
      }
    }
    // reset accumulators for next chunk
#pragma unroll
    for (int r = 0; r < 4; ++r)
#pragma unroll
      for (int t = 0; t < 4; ++t) acc[r][t] = (float4v){0.f, 0.f, 0.f, 0.f};
  }
#undef G2_KK
}

// ---------------------------------------------------------------------------
extern "C" void kernel_launch(void* const* d_in, const int* in_sizes, int n_in,
                              void* d_out, int out_size, void* d_ws, size_t ws_size,
                              hipStream_t stream) {
  const float* x  = (const float*)d_in[0];
  const float* m  = (const float*)d_in[1];
  const float* s  = (const float*)d_in[2];
  const float* W1 = (const float*)d_in[3];
  const float* b1 = (const float*)d_in[4];
  const float* W2 = (const float*)d_in[5];
  const float* b2 = (const float*)d_in[6];
  float* out = (float*)d_out;

  // ws layout (bytes):
  //   feat  bf16 : [0, 150994944)               36*65536*32 elems
  //   W1s   bf16 : [150994944, 152322048)       1152*576
  //   W2s   bf16 : [152322048, 161759232)       1152*4096 (o-major permuted)
  //   yr/mr/sr f32: 3 x 16777216 from 161759232 ; end = 212090880
  if (ws_size < 212090880ull) return;
  char* ws = (char*)d_ws;
  unsigned short* featb = (unsigned short*)ws;
  unsigned short* W1s   = (unsigned short*)(ws + 150994944);
  unsigned short* W2s   = (unsigned short*)(ws + 152322048);
  float* yr = (float*)(ws + 161759232);
  float* mr = (float*)(ws + 178536448);
  float* sr = (float*)(ws + 195313664);

  k_feat<<<36864, 256, 0, stream>>>(x, m, featb);
  k_sw<<<324, 256, 0, stream>>>(W1, W1s, 576, 36, 82944, 0);
  k_sw<<<2304, 256, 0, stream>>>(W2, W2s, 4096, 256, 589824, 1);
  dim3 g1(512, 4);
  k_gemm1<<<g1, 512, 0, stream>>>(featb, W1s, b1, x, m, s, yr, mr, sr);
  k_gemm2<<<512, 512, 0, stream>>>(featb, W2s, b2, yr, mr, sr, out);
}